// Round 16
// baseline (271.337 us; speedup 1.0000x reference)
//
#include <hip/hip_runtime.h>
#include <hip/hip_bf16.h>
#include <stdint.h>

typedef float  f32x4  __attribute__((ext_vector_type(4)));
typedef float  f32x2  __attribute__((ext_vector_type(2)));
typedef short  s16x8  __attribute__((ext_vector_type(8)));
typedef unsigned short u16;

#define DEVI __device__ __forceinline__

DEVI u16 f2bf(float x) {
  union { __hip_bfloat16 b; u16 u; } c;
  c.b = __float2bfloat16(x);            // RNE
  return c.u;
}
DEVI float bf2f(u16 h) { return __uint_as_float(((uint32_t)h) << 16); }

// Row permutation: exp-sensitive rows (m=2,3,87,88,172,173) -> permuted rows 0..5
// so the hi/lo correction MFMA only touches fragment rows 0..15 (wave 0).
DEVI int unperm(int pr) {
  if (pr < 6) return 85 * (pr >> 1) + 2 + (pr & 1);
  int idx = pr - 6;
  return idx + (idx < 2 ? 0 : (idx < 85 ? 2 : (idx < 168 ? 4 : 6)));
}

template<int HEAD> DEVI float anchW(int a) {
  if constexpr (HEAD == 0) return a == 0 ? 116.f/416.f : (a == 1 ? 156.f/416.f : 373.f/416.f);
  else if constexpr (HEAD == 1) return a == 0 ? 30.f/416.f : (a == 1 ? 62.f/416.f : 59.f/416.f);
  else return a == 0 ? 10.f/416.f : (a == 1 ? 16.f/416.f : 33.f/416.f);
}
template<int HEAD> DEVI float anchH(int a) {
  if constexpr (HEAD == 0) return a == 0 ? 90.f/416.f : (a == 1 ? 198.f/416.f : 326.f/416.f);
  else if constexpr (HEAD == 1) return a == 0 ? 61.f/416.f : (a == 1 ? 45.f/416.f : 119.f/416.f);
  else return a == 0 ? 13.f/416.f : (a == 1 ? 30.f/416.f : 23.f/416.f);
}

// ---------------- W pre-pack (fragment-linear, unchanged from R7+) ----------------
template<int K, int LOGK>
DEVI void pack_head(const float* __restrict__ Wt, u16* __restrict__ dst,
                    int i, int alBaseWords) {
  const int pr = i >> LOGK;
  const int k  = i & (K - 1);
  float x = 0.f;
  if (pr < 255) x = Wt[(size_t)unperm(pr) * K + k];
  const u16 hi = f2bf(x);
  const int t    = k >> 5;
  const int rb   = pr >> 4;
  const int lane = (pr & 15) | (((k >> 3) & 3) << 4);
  const int elem = k & 7;
  dst[((size_t)(t * 16 + rb)) * 512 + lane * 8 + elem] = hi;
  if (pr < 16)
    dst[(size_t)alBaseWords + (size_t)t * 512 + lane * 8 + elem] = f2bf(x - bf2f(hi));
}

__global__ __launch_bounds__(256)
void pack_all(const float* __restrict__ W13, const float* __restrict__ W26,
              const float* __restrict__ W52, u16* __restrict__ p13,
              u16* __restrict__ p26, u16* __restrict__ p52) {
  const int g = (int)(blockIdx.x * 256 + threadIdx.x);
  if (g < 262144)       pack_head<1024, 10>(W13, p13, g,            262144);
  else if (g < 393216)  pack_head< 512,  9>(W26, p26, g - 262144,   131072);
  else                  pack_head< 256,  8>(W52, p52, g - 393216,    65536);
}

struct Shm {
  float raw[256 * 17];
  float bias[256];
  u16   perm[256];
  f32x2 cw[16];
};

// ---------------- fused GEMM + lean decode ----------------
// R11 structure + (a) B pipeline 4-deep (lookahead ~3.5 steps covers ~900cyc HBM
// latency; R11's 1.5-step lookahead left every wave stalled ~600cyc/step) at
// __launch_bounds__(256,5) (R12 lesson: +20 regs at (256,6) spills -> +56MB WRITE).
// A stays just-in-time (R12: A-dbuf was the spill trigger, and A is L2-resident).
template<int K, int WD, int HEAD>
DEVI void head_block(const float* __restrict__ F, const u16* __restrict__ Wp,
                     const float* __restrict__ bias_g, float* __restrict__ out,
                     int bidx, Shm* sh)
{
  constexpr int S  = WD * WD;
  constexpr int NT = (S + 15) / 16;
  constexpr int NSTEP = K / 32;          // 32/16/8 — divisible by 4
  constexpr float invWD = 1.f / (float)WD;

  const int b  = bidx / NT;
  const int s0 = (bidx - b * NT) * 16;
  const int tid  = (int)threadIdx.x;
  const int lane = tid & 63;
  const int wmu  = (int)__builtin_amdgcn_readfirstlane((unsigned)(tid >> 6));
  const int ridx = lane & 15;
  const int g8   = (lane >> 4) << 3;

  // ---- per-block tables ----
  {
    const int m_of = unperm(tid);
    sh->perm[m_of] = (u16)tid;
    sh->bias[tid] = (tid < 255) ? bias_g[m_of] : 0.f;
    if (tid < 16) {
      int s = s0 + tid; if (s >= S) s = S - 1;
      const int hh = s / WD;
      const int ww = s - hh * WD;
      sh->cw[tid] = f32x2{(float)ww * invWD, (float)hh * invWD};
    }
  }

  const float* Fb = F + (size_t)b * K * S;
  const int bc   = s0 + ridx;
  const int bcol = bc < S ? bc : S - 1;
  int boff[8];
  #pragma unroll
  for (int e = 0; e < 8; ++e) boff[e] = (g8 + e) * S + bcol;

  const u16* Abase  = Wp + (size_t)wmu * 4 * 512 + lane * 8;
  const u16* Albase = Wp + (size_t)K * 256 + lane * 8;

  f32x4 acc[4];
  #pragma unroll
  for (int i = 0; i < 4; ++i)
    #pragma unroll
    for (int r = 0; r < 4; ++r) acc[i][r] = 0.f;

  s16x8 A[4], Alo;
  float B0[8], B1[8], B2[8], B3[8];

#define LOADA(tt) do {                                                        \
    const u16* ap_ = Abase + (size_t)(tt) * 16 * 512;                         \
    A[0] = *(const s16x8*)(ap_);                                              \
    A[1] = *(const s16x8*)(ap_ + 512);                                        \
    A[2] = *(const s16x8*)(ap_ + 1024);                                       \
    A[3] = *(const s16x8*)(ap_ + 1536);                                       \
    if (wmu == 0) Alo = *(const s16x8*)(Albase + (size_t)(tt) * 512);         \
  } while (0)

#define LOADB(Bx, tt) do {                                                    \
    const float* fp_ = Fb + (size_t)(tt) * 32 * S;                            \
    _Pragma("unroll")                                                         \
    for (int e_ = 0; e_ < 8; ++e_) Bx[e_] = fp_[boff[e_]];                    \
  } while (0)

#define COMPUTE(Bx) do {                                                      \
    u16 bh_[8]; s16x8 Bh_;                                                    \
    _Pragma("unroll")                                                         \
    for (int e_ = 0; e_ < 8; ++e_) { bh_[e_] = f2bf(Bx[e_]); Bh_[e_] = (short)bh_[e_]; } \
    _Pragma("unroll")                                                         \
    for (int mf_ = 0; mf_ < 4; ++mf_)                                         \
      acc[mf_] = __builtin_amdgcn_mfma_f32_16x16x32_bf16(A[mf_], Bh_, acc[mf_], 0, 0, 0); \
    if (wmu == 0) {                                                           \
      s16x8 Bl_;                                                              \
      _Pragma("unroll")                                                       \
      for (int e_ = 0; e_ < 8; ++e_) Bl_[e_] = (short)f2bf(Bx[e_] - bf2f(bh_[e_])); \
      acc[0] = __builtin_amdgcn_mfma_f32_16x16x32_bf16(A[0], Bl_, acc[0], 0, 0, 0); \
      acc[0] = __builtin_amdgcn_mfma_f32_16x16x32_bf16(Alo, Bh_, acc[0], 0, 0, 0); \
    }                                                                         \
  } while (0)

  // ---- K-loop: B 4-deep (lookahead ~3.5 steps), A just-in-time, no barriers ----
  LOADB(B0, 0); LOADB(B1, 1); LOADB(B2, 2); LOADB(B3, 3);
  for (int t = 0; t < NSTEP; t += 4) {
    LOADA(t);     COMPUTE(B0); if (t + 4 < NSTEP) LOADB(B0, t + 4);
    LOADA(t + 1); COMPUTE(B1); if (t + 5 < NSTEP) LOADB(B1, t + 5);
    LOADA(t + 2); COMPUTE(B2); if (t + 6 < NSTEP) LOADB(B2, t + 6);
    LOADA(t + 3); COMPUTE(B3); if (t + 7 < NSTEP) LOADB(B3, t + 7);
  }

#undef LOADA
#undef LOADB
#undef COMPUTE

  // ---- dump raw p-values (+bias) into LDS, fragment-native indexing ----
  #pragma unroll
  for (int mf = 0; mf < 4; ++mf)
    #pragma unroll
    for (int r = 0; r < 4; ++r) {
      const int pr = wmu * 64 + mf * 16 + ((lane >> 4) << 2) + r;
      sh->raw[pr * 17 + ridx] = acc[mf][r] + sh->bias[pr];
    }
  __syncthreads();

  // ---- output-linear decode ----
  const int vs = (S - s0) < 16 ? (S - s0) : 16;
  const int sq0 = tid / 85;
  const int at0 = tid - 85 * sq0;
  #pragma unroll
  for (int a = 0; a < 3; ++a) {
    const float aw = anchW<HEAD>(a);
    const float ah = anchH<HEAD>(a);
    float* oa = out + ((size_t)(b * 3 + a) * S + s0) * 85;
    int i = tid, at = at0, sq = sq0;
    #pragma unroll
    for (int j = 0; j < 6; ++j) {
      if (i < 1360 && sq < vs) {
        const int pr  = (int)sh->perm[a * 85 + at];
        const float p = sh->raw[pr * 17 + sq];
        const float e  = __expf(p);
        const float sg = e * __builtin_amdgcn_rcpf(e + 1.f);
        const f32x2 c  = sh->cw[sq];
        float val;
        if      (at == 0) val = fmaf(sg, invWD, c[0]);
        else if (at == 1) val = fmaf(sg, invWD, c[1]);
        else if (at == 2) val = e * aw;
        else if (at == 3) val = e * ah;
        else              val = sg;
        oa[i] = val;
      }
      i += 256; at += 1; sq += 3;
      if (at >= 85) { at -= 85; sq += 1; }
    }
  }
}

__global__ __launch_bounds__(256, 5)
void yolo_fused(const float* __restrict__ f13, const float* __restrict__ f26,
                const float* __restrict__ f52,
                const u16* __restrict__ p13, const float* __restrict__ b13,
                const u16* __restrict__ p26, const float* __restrict__ b26,
                const u16* __restrict__ p52, const float* __restrict__ b52,
                float* __restrict__ out)
{
  __shared__ Shm sh;
  const int blk = (int)blockIdx.x;
  float* out13 = out;
  float* out26 = out + 1379040;          // 32*507*85
  float* out52 = out + 6895200;          // + 32*2028*85
  // Per-head XCD-bijective chunked swizzle (T1): dispatch d -> XCD d%8 (approx);
  // give each XCD a CONTIGUOUS tile range per head so adjacent 16-wide tiles
  // (which split 128B F-lines) share an L2. 352=8*44, 1376=8*172, 5408=8*676.
  if (blk < 352) {
    const int tile = (blk & 7) * 44 + (blk >> 3);
    head_block<1024, 13, 0>(f13, p13, b13, out13, tile, &sh);
  } else if (blk < 1728) {
    const int i = blk - 352;
    const int tile = (i & 7) * 172 + (i >> 3);
    head_block< 512, 26, 1>(f26, p26, b26, out26, tile, &sh);
  } else {
    const int i = blk - 1728;
    const int tile = (i & 7) * 676 + (i >> 3);
    head_block< 256, 52, 2>(f52, p52, b52, out52, tile, &sh);
  }
}

extern "C" void kernel_launch(void* const* d_in, const int* in_sizes, int n_in,
                              void* d_out, int out_size, void* d_ws, size_t ws_size,
                              hipStream_t stream) {
  (void)in_sizes; (void)n_in; (void)ws_size; (void)out_size;
  const float* f13 = (const float*)d_in[0];
  const float* f26 = (const float*)d_in[1];
  const float* f52 = (const float*)d_in[2];
  const float* W13 = (const float*)d_in[3];
  const float* b13 = (const float*)d_in[4];
  const float* W26 = (const float*)d_in[5];
  const float* b26 = (const float*)d_in[6];
  const float* W52 = (const float*)d_in[7];
  const float* b52 = (const float*)d_in[8];

  u16* p13 = (u16*)d_ws;                 // 278528 u16
  u16* p26 = p13 + 278528;               // 139264 u16
  u16* p52 = p26 + 139264;               //  69632 u16 (total 974848 B)

  pack_all<<<dim3(1792), dim3(256), 0, stream>>>(W13, W26, W52, p13, p26, p52);
  yolo_fused<<<dim3(7136), dim3(256), 0, stream>>>(
      f13, f26, f52, p13, b13, p26, b26, p52, b52, (float*)d_out);
}

// Round 17
// 149.433 us; speedup vs baseline: 1.8158x; 1.8158x over previous
//
#include <hip/hip_runtime.h>
#include <hip/hip_bf16.h>
#include <stdint.h>

typedef float  f32x4  __attribute__((ext_vector_type(4)));
typedef float  f32x2  __attribute__((ext_vector_type(2)));
typedef short  s16x8  __attribute__((ext_vector_type(8)));
typedef unsigned short u16;

#define DEVI __device__ __forceinline__

DEVI u16 f2bf(float x) {
  union { __hip_bfloat16 b; u16 u; } c;
  c.b = __float2bfloat16(x);            // RNE
  return c.u;
}
DEVI float bf2f(u16 h) { return __uint_as_float(((uint32_t)h) << 16); }

// Row permutation: exp-sensitive rows (m=2,3,87,88,172,173) -> permuted rows 0..5
// so the hi/lo correction MFMA only touches fragment rows 0..15 (wave 0).
DEVI int unperm(int pr) {
  if (pr < 6) return 85 * (pr >> 1) + 2 + (pr & 1);
  int idx = pr - 6;
  return idx + (idx < 2 ? 0 : (idx < 85 ? 2 : (idx < 168 ? 4 : 6)));
}

template<int HEAD> DEVI float anchW(int a) {
  if constexpr (HEAD == 0) return a == 0 ? 116.f/416.f : (a == 1 ? 156.f/416.f : 373.f/416.f);
  else if constexpr (HEAD == 1) return a == 0 ? 30.f/416.f : (a == 1 ? 62.f/416.f : 59.f/416.f);
  else return a == 0 ? 10.f/416.f : (a == 1 ? 16.f/416.f : 33.f/416.f);
}
template<int HEAD> DEVI float anchH(int a) {
  if constexpr (HEAD == 0) return a == 0 ? 90.f/416.f : (a == 1 ? 198.f/416.f : 326.f/416.f);
  else if constexpr (HEAD == 1) return a == 0 ? 61.f/416.f : (a == 1 ? 45.f/416.f : 119.f/416.f);
  else return a == 0 ? 13.f/416.f : (a == 1 ? 30.f/416.f : 23.f/416.f);
}

// ---------------- W pre-pack (fragment-linear, unchanged from R7+) ----------------
template<int K, int LOGK>
DEVI void pack_head(const float* __restrict__ Wt, u16* __restrict__ dst,
                    int i, int alBaseWords) {
  const int pr = i >> LOGK;
  const int k  = i & (K - 1);
  float x = 0.f;
  if (pr < 255) x = Wt[(size_t)unperm(pr) * K + k];
  const u16 hi = f2bf(x);
  const int t    = k >> 5;
  const int rb   = pr >> 4;
  const int lane = (pr & 15) | (((k >> 3) & 3) << 4);
  const int elem = k & 7;
  dst[((size_t)(t * 16 + rb)) * 512 + lane * 8 + elem] = hi;
  if (pr < 16)
    dst[(size_t)alBaseWords + (size_t)t * 512 + lane * 8 + elem] = f2bf(x - bf2f(hi));
}

__global__ __launch_bounds__(256)
void pack_all(const float* __restrict__ W13, const float* __restrict__ W26,
              const float* __restrict__ W52, u16* __restrict__ p13,
              u16* __restrict__ p26, u16* __restrict__ p52) {
  const int g = (int)(blockIdx.x * 256 + threadIdx.x);
  if (g < 262144)       pack_head<1024, 10>(W13, p13, g,            262144);
  else if (g < 393216)  pack_head< 512,  9>(W26, p26, g - 262144,   131072);
  else                  pack_head< 256,  8>(W52, p52, g - 393216,    65536);
}

struct Shm {
  float raw[256 * 17];
  float bias[256];
  u16   perm[256];
  f32x2 cw[16];
};

// ---------------- fused GEMM + lean decode ----------------
// EXACT R11 structure (124us, VGPR 36, zero spill): B 2-deep (1.5-step lookahead),
// A just-in-time, barrier-free K-loop. R12/R16 lesson: ANY register growth beyond
// this live set spills (A-dbuf +20 -> +56MB WRITE; B-4deep +16 -> +281MB WRITE).
// This round's levers are register-free: occupancy 6->8 waves/SIMD via
// __launch_bounds__(256,8) (cap 64 >= measured 52 arch+acc), and the per-head
// XCD swizzle (FETCH 232 vs 155 logical = 64B half-line over-read).
template<int K, int WD, int HEAD>
DEVI void head_block(const float* __restrict__ F, const u16* __restrict__ Wp,
                     const float* __restrict__ bias_g, float* __restrict__ out,
                     int bidx, Shm* sh)
{
  constexpr int S  = WD * WD;
  constexpr int NT = (S + 15) / 16;
  constexpr int NSTEP = K / 32;          // 32/16/8 — even
  constexpr float invWD = 1.f / (float)WD;

  const int b  = bidx / NT;
  const int s0 = (bidx - b * NT) * 16;
  const int tid  = (int)threadIdx.x;
  const int lane = tid & 63;
  const int wmu  = (int)__builtin_amdgcn_readfirstlane((unsigned)(tid >> 6));
  const int ridx = lane & 15;
  const int g8   = (lane >> 4) << 3;

  // ---- per-block tables ----
  {
    const int m_of = unperm(tid);
    sh->perm[m_of] = (u16)tid;
    sh->bias[tid] = (tid < 255) ? bias_g[m_of] : 0.f;
    if (tid < 16) {
      int s = s0 + tid; if (s >= S) s = S - 1;
      const int hh = s / WD;
      const int ww = s - hh * WD;
      sh->cw[tid] = f32x2{(float)ww * invWD, (float)hh * invWD};
    }
  }

  const float* Fb = F + (size_t)b * K * S;
  const int bc   = s0 + ridx;
  const int bcol = bc < S ? bc : S - 1;
  int boff[8];
  #pragma unroll
  for (int e = 0; e < 8; ++e) boff[e] = (g8 + e) * S + bcol;

  const u16* Abase  = Wp + (size_t)wmu * 4 * 512 + lane * 8;
  const u16* Albase = Wp + (size_t)K * 256 + lane * 8;

  f32x4 acc[4];
  #pragma unroll
  for (int i = 0; i < 4; ++i)
    #pragma unroll
    for (int r = 0; r < 4; ++r) acc[i][r] = 0.f;

  s16x8 A[4], Alo;
  float B0[8], B1[8];

#define LOADA(tt) do {                                                        \
    const u16* ap_ = Abase + (size_t)(tt) * 16 * 512;                         \
    A[0] = *(const s16x8*)(ap_);                                              \
    A[1] = *(const s16x8*)(ap_ + 512);                                        \
    A[2] = *(const s16x8*)(ap_ + 1024);                                       \
    A[3] = *(const s16x8*)(ap_ + 1536);                                       \
    if (wmu == 0) Alo = *(const s16x8*)(Albase + (size_t)(tt) * 512);         \
  } while (0)

#define LOADB(Bx, tt) do {                                                    \
    const float* fp_ = Fb + (size_t)(tt) * 32 * S;                            \
    _Pragma("unroll")                                                         \
    for (int e_ = 0; e_ < 8; ++e_) Bx[e_] = fp_[boff[e_]];                    \
  } while (0)

#define COMPUTE(Bx) do {                                                      \
    u16 bh_[8]; s16x8 Bh_;                                                    \
    _Pragma("unroll")                                                         \
    for (int e_ = 0; e_ < 8; ++e_) { bh_[e_] = f2bf(Bx[e_]); Bh_[e_] = (short)bh_[e_]; } \
    _Pragma("unroll")                                                         \
    for (int mf_ = 0; mf_ < 4; ++mf_)                                         \
      acc[mf_] = __builtin_amdgcn_mfma_f32_16x16x32_bf16(A[mf_], Bh_, acc[mf_], 0, 0, 0); \
    if (wmu == 0) {                                                           \
      s16x8 Bl_;                                                              \
      _Pragma("unroll")                                                       \
      for (int e_ = 0; e_ < 8; ++e_) Bl_[e_] = (short)f2bf(Bx[e_] - bf2f(bh_[e_])); \
      acc[0] = __builtin_amdgcn_mfma_f32_16x16x32_bf16(A[0], Bl_, acc[0], 0, 0, 0); \
      acc[0] = __builtin_amdgcn_mfma_f32_16x16x32_bf16(Alo, Bh_, acc[0], 0, 0, 0); \
    }                                                                         \
  } while (0)

  // ---- K-loop: B one step ahead, A just-in-time, no barriers (R11-exact) ----
  LOADB(B0, 0);
  LOADB(B1, 1);
  for (int t = 0; t < NSTEP; t += 2) {
    LOADA(t);
    COMPUTE(B0);
    if (t + 2 < NSTEP) LOADB(B0, t + 2);
    LOADA(t + 1);
    COMPUTE(B1);
    if (t + 3 < NSTEP) LOADB(B1, t + 3);
  }

#undef LOADA
#undef LOADB
#undef COMPUTE

  // ---- dump raw p-values (+bias) into LDS, fragment-native indexing ----
  #pragma unroll
  for (int mf = 0; mf < 4; ++mf)
    #pragma unroll
    for (int r = 0; r < 4; ++r) {
      const int pr = wmu * 64 + mf * 16 + ((lane >> 4) << 2) + r;
      sh->raw[pr * 17 + ridx] = acc[mf][r] + sh->bias[pr];
    }
  __syncthreads();

  // ---- output-linear decode ----
  const int vs = (S - s0) < 16 ? (S - s0) : 16;
  const int sq0 = tid / 85;
  const int at0 = tid - 85 * sq0;
  #pragma unroll
  for (int a = 0; a < 3; ++a) {
    const float aw = anchW<HEAD>(a);
    const float ah = anchH<HEAD>(a);
    float* oa = out + ((size_t)(b * 3 + a) * S + s0) * 85;
    int i = tid, at = at0, sq = sq0;
    #pragma unroll
    for (int j = 0; j < 6; ++j) {
      if (i < 1360 && sq < vs) {
        const int pr  = (int)sh->perm[a * 85 + at];
        const float p = sh->raw[pr * 17 + sq];
        const float e  = __expf(p);
        const float sg = e * __builtin_amdgcn_rcpf(e + 1.f);
        const f32x2 c  = sh->cw[sq];
        float val;
        if      (at == 0) val = fmaf(sg, invWD, c[0]);
        else if (at == 1) val = fmaf(sg, invWD, c[1]);
        else if (at == 2) val = e * aw;
        else if (at == 3) val = e * ah;
        else              val = sg;
        oa[i] = val;
      }
      i += 256; at += 1; sq += 3;
      if (at >= 85) { at -= 85; sq += 1; }
    }
  }
}

__global__ __launch_bounds__(256, 8)
void yolo_fused(const float* __restrict__ f13, const float* __restrict__ f26,
                const float* __restrict__ f52,
                const u16* __restrict__ p13, const float* __restrict__ b13,
                const u16* __restrict__ p26, const float* __restrict__ b26,
                const u16* __restrict__ p52, const float* __restrict__ b52,
                float* __restrict__ out)
{
  __shared__ Shm sh;
  const int blk = (int)blockIdx.x;
  float* out13 = out;
  float* out26 = out + 1379040;          // 32*507*85
  float* out52 = out + 6895200;          // + 32*2028*85
  // Per-head XCD-bijective chunked swizzle (T1): adjacent 16-wide tiles share
  // 128B F-lines; chunking keeps them on the same XCD L2. 352=8*44, 1376=8*172,
  // 5408=8*676 (all divisible by 8 -> bijective, load-balanced).
  if (blk < 352) {
    const int tile = (blk & 7) * 44 + (blk >> 3);
    head_block<1024, 13, 0>(f13, p13, b13, out13, tile, &sh);
  } else if (blk < 1728) {
    const int i = blk - 352;
    const int tile = (i & 7) * 172 + (i >> 3);
    head_block< 512, 26, 1>(f26, p26, b26, out26, tile, &sh);
  } else {
    const int i = blk - 1728;
    const int tile = (i & 7) * 676 + (i >> 3);
    head_block< 256, 52, 2>(f52, p52, b52, out52, tile, &sh);
  }
}

extern "C" void kernel_launch(void* const* d_in, const int* in_sizes, int n_in,
                              void* d_out, int out_size, void* d_ws, size_t ws_size,
                              hipStream_t stream) {
  (void)in_sizes; (void)n_in; (void)ws_size; (void)out_size;
  const float* f13 = (const float*)d_in[0];
  const float* f26 = (const float*)d_in[1];
  const float* f52 = (const float*)d_in[2];
  const float* W13 = (const float*)d_in[3];
  const float* b13 = (const float*)d_in[4];
  const float* W26 = (const float*)d_in[5];
  const float* b26 = (const float*)d_in[6];
  const float* W52 = (const float*)d_in[7];
  const float* b52 = (const float*)d_in[8];

  u16* p13 = (u16*)d_ws;                 // 278528 u16
  u16* p26 = p13 + 278528;               // 139264 u16
  u16* p52 = p26 + 139264;               //  69632 u16 (total 974848 B)

  pack_all<<<dim3(1792), dim3(256), 0, stream>>>(W13, W26, W52, p13, p26, p52);
  yolo_fused<<<dim3(7136), dim3(256), 0, stream>>>(
      f13, f26, f52, p13, b13, p26, b26, p52, b52, (float*)d_out);
}

// Round 18
// 139.484 us; speedup vs baseline: 1.9453x; 1.0713x over previous
//
#include <hip/hip_runtime.h>
#include <hip/hip_bf16.h>
#include <stdint.h>

typedef float  f32x4  __attribute__((ext_vector_type(4)));
typedef float  f32x2  __attribute__((ext_vector_type(2)));
typedef short  s16x8  __attribute__((ext_vector_type(8)));
typedef unsigned short u16;

#define DEVI __device__ __forceinline__

DEVI u16 f2bf(float x) {
  union { __hip_bfloat16 b; u16 u; } c;
  c.b = __float2bfloat16(x);            // RNE
  return c.u;
}
DEVI float bf2f(u16 h) { return __uint_as_float(((uint32_t)h) << 16); }

// Row permutation: exp-sensitive rows (m=2,3,87,88,172,173) -> permuted rows 0..5
// so the hi/lo correction MFMA only touches fragment rows 0..15 (wave 0).
DEVI int unperm(int pr) {
  if (pr < 6) return 85 * (pr >> 1) + 2 + (pr & 1);
  int idx = pr - 6;
  return idx + (idx < 2 ? 0 : (idx < 85 ? 2 : (idx < 168 ? 4 : 6)));
}

template<int HEAD> DEVI float anchW(int a) {
  if constexpr (HEAD == 0) return a == 0 ? 116.f/416.f : (a == 1 ? 156.f/416.f : 373.f/416.f);
  else if constexpr (HEAD == 1) return a == 0 ? 30.f/416.f : (a == 1 ? 62.f/416.f : 59.f/416.f);
  else return a == 0 ? 10.f/416.f : (a == 1 ? 16.f/416.f : 33.f/416.f);
}
template<int HEAD> DEVI float anchH(int a) {
  if constexpr (HEAD == 0) return a == 0 ? 90.f/416.f : (a == 1 ? 198.f/416.f : 326.f/416.f);
  else if constexpr (HEAD == 1) return a == 0 ? 61.f/416.f : (a == 1 ? 45.f/416.f : 119.f/416.f);
  else return a == 0 ? 13.f/416.f : (a == 1 ? 30.f/416.f : 23.f/416.f);
}

// ---------------- W pre-pack (fragment-linear, unchanged from R7+) ----------------
template<int K, int LOGK>
DEVI void pack_head(const float* __restrict__ Wt, u16* __restrict__ dst,
                    int i, int alBaseWords) {
  const int pr = i >> LOGK;
  const int k  = i & (K - 1);
  float x = 0.f;
  if (pr < 255) x = Wt[(size_t)unperm(pr) * K + k];
  const u16 hi = f2bf(x);
  const int t    = k >> 5;
  const int rb   = pr >> 4;
  const int lane = (pr & 15) | (((k >> 3) & 3) << 4);
  const int elem = k & 7;
  dst[((size_t)(t * 16 + rb)) * 512 + lane * 8 + elem] = hi;
  if (pr < 16)
    dst[(size_t)alBaseWords + (size_t)t * 512 + lane * 8 + elem] = f2bf(x - bf2f(hi));
}

__global__ __launch_bounds__(256)
void pack_all(const float* __restrict__ W13, const float* __restrict__ W26,
              const float* __restrict__ W52, u16* __restrict__ p13,
              u16* __restrict__ p26, u16* __restrict__ p52) {
  const int g = (int)(blockIdx.x * 256 + threadIdx.x);
  if (g < 262144)       pack_head<1024, 10>(W13, p13, g,            262144);
  else if (g < 393216)  pack_head< 512,  9>(W26, p26, g - 262144,   131072);
  else                  pack_head< 256,  8>(W52, p52, g - 393216,    65536);
}

struct Shm {
  float raw[256 * 17];
  float bias[256];
  u16   perm[256];
  f32x2 cw[16];
};

// ---------------- fused GEMM + lean decode ----------------
// EXACT R11 structure (124us, VGPR 36, zero spill) + per-head XCD swizzle ONLY.
// R17 lesson: swizzle collapses FETCH 232->98MB (B-loads become L2-hits, ~200-400
// cyc — coverable by the existing 1.5-step lookahead), but (256,8) squeezed VGPR
// 36->32 and spilled in-loop (+22MB WRITE) which ate the gain. This round keeps
// (256,6) so the register budget is R11-identical; single variable = swizzle.
template<int K, int WD, int HEAD>
DEVI void head_block(const float* __restrict__ F, const u16* __restrict__ Wp,
                     const float* __restrict__ bias_g, float* __restrict__ out,
                     int bidx, Shm* sh)
{
  constexpr int S  = WD * WD;
  constexpr int NT = (S + 15) / 16;
  constexpr int NSTEP = K / 32;          // 32/16/8 — even
  constexpr float invWD = 1.f / (float)WD;

  const int b  = bidx / NT;
  const int s0 = (bidx - b * NT) * 16;
  const int tid  = (int)threadIdx.x;
  const int lane = tid & 63;
  const int wmu  = (int)__builtin_amdgcn_readfirstlane((unsigned)(tid >> 6));
  const int ridx = lane & 15;
  const int g8   = (lane >> 4) << 3;

  // ---- per-block tables ----
  {
    const int m_of = unperm(tid);
    sh->perm[m_of] = (u16)tid;
    sh->bias[tid] = (tid < 255) ? bias_g[m_of] : 0.f;
    if (tid < 16) {
      int s = s0 + tid; if (s >= S) s = S - 1;
      const int hh = s / WD;
      const int ww = s - hh * WD;
      sh->cw[tid] = f32x2{(float)ww * invWD, (float)hh * invWD};
    }
  }

  const float* Fb = F + (size_t)b * K * S;
  const int bc   = s0 + ridx;
  const int bcol = bc < S ? bc : S - 1;
  int boff[8];
  #pragma unroll
  for (int e = 0; e < 8; ++e) boff[e] = (g8 + e) * S + bcol;

  const u16* Abase  = Wp + (size_t)wmu * 4 * 512 + lane * 8;
  const u16* Albase = Wp + (size_t)K * 256 + lane * 8;

  f32x4 acc[4];
  #pragma unroll
  for (int i = 0; i < 4; ++i)
    #pragma unroll
    for (int r = 0; r < 4; ++r) acc[i][r] = 0.f;

  s16x8 A[4], Alo;
  float B0[8], B1[8];

#define LOADA(tt) do {                                                        \
    const u16* ap_ = Abase + (size_t)(tt) * 16 * 512;                         \
    A[0] = *(const s16x8*)(ap_);                                              \
    A[1] = *(const s16x8*)(ap_ + 512);                                        \
    A[2] = *(const s16x8*)(ap_ + 1024);                                       \
    A[3] = *(const s16x8*)(ap_ + 1536);                                       \
    if (wmu == 0) Alo = *(const s16x8*)(Albase + (size_t)(tt) * 512);         \
  } while (0)

#define LOADB(Bx, tt) do {                                                    \
    const float* fp_ = Fb + (size_t)(tt) * 32 * S;                            \
    _Pragma("unroll")                                                         \
    for (int e_ = 0; e_ < 8; ++e_) Bx[e_] = fp_[boff[e_]];                    \
  } while (0)

#define COMPUTE(Bx) do {                                                      \
    u16 bh_[8]; s16x8 Bh_;                                                    \
    _Pragma("unroll")                                                         \
    for (int e_ = 0; e_ < 8; ++e_) { bh_[e_] = f2bf(Bx[e_]); Bh_[e_] = (short)bh_[e_]; } \
    _Pragma("unroll")                                                         \
    for (int mf_ = 0; mf_ < 4; ++mf_)                                         \
      acc[mf_] = __builtin_amdgcn_mfma_f32_16x16x32_bf16(A[mf_], Bh_, acc[mf_], 0, 0, 0); \
    if (wmu == 0) {                                                           \
      s16x8 Bl_;                                                              \
      _Pragma("unroll")                                                       \
      for (int e_ = 0; e_ < 8; ++e_) Bl_[e_] = (short)f2bf(Bx[e_] - bf2f(bh_[e_])); \
      acc[0] = __builtin_amdgcn_mfma_f32_16x16x32_bf16(A[0], Bl_, acc[0], 0, 0, 0); \
      acc[0] = __builtin_amdgcn_mfma_f32_16x16x32_bf16(Alo, Bh_, acc[0], 0, 0, 0); \
    }                                                                         \
  } while (0)

  // ---- K-loop: B one step ahead, A just-in-time, no barriers (R11-exact) ----
  LOADB(B0, 0);
  LOADB(B1, 1);
  for (int t = 0; t < NSTEP; t += 2) {
    LOADA(t);
    COMPUTE(B0);
    if (t + 2 < NSTEP) LOADB(B0, t + 2);
    LOADA(t + 1);
    COMPUTE(B1);
    if (t + 3 < NSTEP) LOADB(B1, t + 3);
  }

#undef LOADA
#undef LOADB
#undef COMPUTE

  // ---- dump raw p-values (+bias) into LDS, fragment-native indexing ----
  #pragma unroll
  for (int mf = 0; mf < 4; ++mf)
    #pragma unroll
    for (int r = 0; r < 4; ++r) {
      const int pr = wmu * 64 + mf * 16 + ((lane >> 4) << 2) + r;
      sh->raw[pr * 17 + ridx] = acc[mf][r] + sh->bias[pr];
    }
  __syncthreads();

  // ---- output-linear decode ----
  const int vs = (S - s0) < 16 ? (S - s0) : 16;
  const int sq0 = tid / 85;
  const int at0 = tid - 85 * sq0;
  #pragma unroll
  for (int a = 0; a < 3; ++a) {
    const float aw = anchW<HEAD>(a);
    const float ah = anchH<HEAD>(a);
    float* oa = out + ((size_t)(b * 3 + a) * S + s0) * 85;
    int i = tid, at = at0, sq = sq0;
    #pragma unroll
    for (int j = 0; j < 6; ++j) {
      if (i < 1360 && sq < vs) {
        const int pr  = (int)sh->perm[a * 85 + at];
        const float p = sh->raw[pr * 17 + sq];
        const float e  = __expf(p);
        const float sg = e * __builtin_amdgcn_rcpf(e + 1.f);
        const f32x2 c  = sh->cw[sq];
        float val;
        if      (at == 0) val = fmaf(sg, invWD, c[0]);
        else if (at == 1) val = fmaf(sg, invWD, c[1]);
        else if (at == 2) val = e * aw;
        else if (at == 3) val = e * ah;
        else              val = sg;
        oa[i] = val;
      }
      i += 256; at += 1; sq += 3;
      if (at >= 85) { at -= 85; sq += 1; }
    }
  }
}

__global__ __launch_bounds__(256, 6)
void yolo_fused(const float* __restrict__ f13, const float* __restrict__ f26,
                const float* __restrict__ f52,
                const u16* __restrict__ p13, const float* __restrict__ b13,
                const u16* __restrict__ p26, const float* __restrict__ b26,
                const u16* __restrict__ p52, const float* __restrict__ b52,
                float* __restrict__ out)
{
  __shared__ Shm sh;
  const int blk = (int)blockIdx.x;
  float* out13 = out;
  float* out26 = out + 1379040;          // 32*507*85
  float* out52 = out + 6895200;          // + 32*2028*85
  // Per-head XCD-bijective chunked swizzle (T1): adjacent 16-wide tiles share
  // 128B F-lines; chunking keeps them on the same XCD L2. 352=8*44, 1376=8*172,
  // 5408=8*676 (all divisible by 8 -> bijective, load-balanced).
  // Measured R17: FETCH 232 -> 98 MB.
  if (blk < 352) {
    const int tile = (blk & 7) * 44 + (blk >> 3);
    head_block<1024, 13, 0>(f13, p13, b13, out13, tile, &sh);
  } else if (blk < 1728) {
    const int i = blk - 352;
    const int tile = (i & 7) * 172 + (i >> 3);
    head_block< 512, 26, 1>(f26, p26, b26, out26, tile, &sh);
  } else {
    const int i = blk - 1728;
    const int tile = (i & 7) * 676 + (i >> 3);
    head_block< 256, 52, 2>(f52, p52, b52, out52, tile, &sh);
  }
}

extern "C" void kernel_launch(void* const* d_in, const int* in_sizes, int n_in,
                              void* d_out, int out_size, void* d_ws, size_t ws_size,
                              hipStream_t stream) {
  (void)in_sizes; (void)n_in; (void)ws_size; (void)out_size;
  const float* f13 = (const float*)d_in[0];
  const float* f26 = (const float*)d_in[1];
  const float* f52 = (const float*)d_in[2];
  const float* W13 = (const float*)d_in[3];
  const float* b13 = (const float*)d_in[4];
  const float* W26 = (const float*)d_in[5];
  const float* b26 = (const float*)d_in[6];
  const float* W52 = (const float*)d_in[7];
  const float* b52 = (const float*)d_in[8];

  u16* p13 = (u16*)d_ws;                 // 278528 u16
  u16* p26 = p13 + 278528;               // 139264 u16
  u16* p52 = p26 + 139264;               //  69632 u16 (total 974848 B)

  pack_all<<<dim3(1792), dim3(256), 0, stream>>>(W13, W26, W52, p13, p26, p52);
  yolo_fused<<<dim3(7136), dim3(256), 0, stream>>>(
      f13, f26, f52, p13, b13, p26, b26, p52, b52, (float*)d_out);
}

// Round 19
// 123.447 us; speedup vs baseline: 2.1980x; 1.1299x over previous
//
#include <hip/hip_runtime.h>
#include <hip/hip_bf16.h>
#include <stdint.h>

typedef float  f32x4  __attribute__((ext_vector_type(4)));
typedef float  f32x2  __attribute__((ext_vector_type(2)));
typedef short  s16x8  __attribute__((ext_vector_type(8)));
typedef unsigned short u16;

#define DEVI __device__ __forceinline__

DEVI u16 f2bf(float x) {
  union { __hip_bfloat16 b; u16 u; } c;
  c.b = __float2bfloat16(x);            // RNE
  return c.u;
}
DEVI float bf2f(u16 h) { return __uint_as_float(((uint32_t)h) << 16); }

// Row permutation: exp-sensitive rows (m=2,3,87,88,172,173) -> permuted rows 0..5
// so the hi/lo correction MFMA only touches fragment rows 0..15 (wave 0).
DEVI int unperm(int pr) {
  if (pr < 6) return 85 * (pr >> 1) + 2 + (pr & 1);
  int idx = pr - 6;
  return idx + (idx < 2 ? 0 : (idx < 85 ? 2 : (idx < 168 ? 4 : 6)));
}

template<int HEAD> DEVI float anchW(int a) {
  if constexpr (HEAD == 0) return a == 0 ? 116.f/416.f : (a == 1 ? 156.f/416.f : 373.f/416.f);
  else if constexpr (HEAD == 1) return a == 0 ? 30.f/416.f : (a == 1 ? 62.f/416.f : 59.f/416.f);
  else return a == 0 ? 10.f/416.f : (a == 1 ? 16.f/416.f : 33.f/416.f);
}
template<int HEAD> DEVI float anchH(int a) {
  if constexpr (HEAD == 0) return a == 0 ? 90.f/416.f : (a == 1 ? 198.f/416.f : 326.f/416.f);
  else if constexpr (HEAD == 1) return a == 0 ? 61.f/416.f : (a == 1 ? 45.f/416.f : 119.f/416.f);
  else return a == 0 ? 13.f/416.f : (a == 1 ? 30.f/416.f : 23.f/416.f);
}

// ---------------- W pre-pack (fragment-linear, unchanged from R7+) ----------------
template<int K, int LOGK>
DEVI void pack_head(const float* __restrict__ Wt, u16* __restrict__ dst,
                    int i, int alBaseWords) {
  const int pr = i >> LOGK;
  const int k  = i & (K - 1);
  float x = 0.f;
  if (pr < 255) x = Wt[(size_t)unperm(pr) * K + k];
  const u16 hi = f2bf(x);
  const int t    = k >> 5;
  const int rb   = pr >> 4;
  const int lane = (pr & 15) | (((k >> 3) & 3) << 4);
  const int elem = k & 7;
  dst[((size_t)(t * 16 + rb)) * 512 + lane * 8 + elem] = hi;
  if (pr < 16)
    dst[(size_t)alBaseWords + (size_t)t * 512 + lane * 8 + elem] = f2bf(x - bf2f(hi));
}

__global__ __launch_bounds__(256)
void pack_all(const float* __restrict__ W13, const float* __restrict__ W26,
              const float* __restrict__ W52, u16* __restrict__ p13,
              u16* __restrict__ p26, u16* __restrict__ p52) {
  const int g = (int)(blockIdx.x * 256 + threadIdx.x);
  if (g < 262144)       pack_head<1024, 10>(W13, p13, g,            262144);
  else if (g < 393216)  pack_head< 512,  9>(W26, p26, g - 262144,   131072);
  else                  pack_head< 256,  8>(W52, p52, g - 393216,    65536);
}

struct Shm {
  float raw[256 * 17];
  float bias[256];
  u16   perm[256];
  f32x2 cw[16];
};

// ---------------- fused GEMM + lean decode ----------------
// EXACT R11 structure (bench-best 124us, VGPR 36, zero spill): B 2-deep,
// A just-in-time, barrier-free K-loop, lean output-linear decode.
// R12/R16: any register growth spills (A-dbuf +56MB WRITE; B-4deep +281MB).
// R17: (256,8) cap 64 squeezes VGPR 36->32 -> in-loop spill (+22MB WRITE).
// R18: XCD swizzle cut FETCH 232->80MB but bench regressed (L3-fit steady
// state; m160) -> dropped. This round: (256,7) (cap 73 >= 52 live) for
// 6->7 waves/SIMD, +17% TLP against the uncovered B-load latency.
template<int K, int WD, int HEAD>
DEVI void head_block(const float* __restrict__ F, const u16* __restrict__ Wp,
                     const float* __restrict__ bias_g, float* __restrict__ out,
                     int bidx, Shm* sh)
{
  constexpr int S  = WD * WD;
  constexpr int NT = (S + 15) / 16;
  constexpr int NSTEP = K / 32;          // 32/16/8 — even
  constexpr float invWD = 1.f / (float)WD;

  const int b  = bidx / NT;
  const int s0 = (bidx - b * NT) * 16;
  const int tid  = (int)threadIdx.x;
  const int lane = tid & 63;
  const int wmu  = (int)__builtin_amdgcn_readfirstlane((unsigned)(tid >> 6));
  const int ridx = lane & 15;
  const int g8   = (lane >> 4) << 3;

  // ---- per-block tables ----
  {
    const int m_of = unperm(tid);
    sh->perm[m_of] = (u16)tid;
    sh->bias[tid] = (tid < 255) ? bias_g[m_of] : 0.f;
    if (tid < 16) {
      int s = s0 + tid; if (s >= S) s = S - 1;
      const int hh = s / WD;
      const int ww = s - hh * WD;
      sh->cw[tid] = f32x2{(float)ww * invWD, (float)hh * invWD};
    }
  }

  const float* Fb = F + (size_t)b * K * S;
  const int bc   = s0 + ridx;
  const int bcol = bc < S ? bc : S - 1;
  int boff[8];
  #pragma unroll
  for (int e = 0; e < 8; ++e) boff[e] = (g8 + e) * S + bcol;

  const u16* Abase  = Wp + (size_t)wmu * 4 * 512 + lane * 8;
  const u16* Albase = Wp + (size_t)K * 256 + lane * 8;

  f32x4 acc[4];
  #pragma unroll
  for (int i = 0; i < 4; ++i)
    #pragma unroll
    for (int r = 0; r < 4; ++r) acc[i][r] = 0.f;

  s16x8 A[4], Alo;
  float B0[8], B1[8];

#define LOADA(tt) do {                                                        \
    const u16* ap_ = Abase + (size_t)(tt) * 16 * 512;                         \
    A[0] = *(const s16x8*)(ap_);                                              \
    A[1] = *(const s16x8*)(ap_ + 512);                                        \
    A[2] = *(const s16x8*)(ap_ + 1024);                                       \
    A[3] = *(const s16x8*)(ap_ + 1536);                                       \
    if (wmu == 0) Alo = *(const s16x8*)(Albase + (size_t)(tt) * 512);         \
  } while (0)

#define LOADB(Bx, tt) do {                                                    \
    const float* fp_ = Fb + (size_t)(tt) * 32 * S;                            \
    _Pragma("unroll")                                                         \
    for (int e_ = 0; e_ < 8; ++e_) Bx[e_] = fp_[boff[e_]];                    \
  } while (0)

#define COMPUTE(Bx) do {                                                      \
    u16 bh_[8]; s16x8 Bh_;                                                    \
    _Pragma("unroll")                                                         \
    for (int e_ = 0; e_ < 8; ++e_) { bh_[e_] = f2bf(Bx[e_]); Bh_[e_] = (short)bh_[e_]; } \
    _Pragma("unroll")                                                         \
    for (int mf_ = 0; mf_ < 4; ++mf_)                                         \
      acc[mf_] = __builtin_amdgcn_mfma_f32_16x16x32_bf16(A[mf_], Bh_, acc[mf_], 0, 0, 0); \
    if (wmu == 0) {                                                           \
      s16x8 Bl_;                                                              \
      _Pragma("unroll")                                                       \
      for (int e_ = 0; e_ < 8; ++e_) Bl_[e_] = (short)f2bf(Bx[e_] - bf2f(bh_[e_])); \
      acc[0] = __builtin_amdgcn_mfma_f32_16x16x32_bf16(A[0], Bl_, acc[0], 0, 0, 0); \
      acc[0] = __builtin_amdgcn_mfma_f32_16x16x32_bf16(Alo, Bh_, acc[0], 0, 0, 0); \
    }                                                                         \
  } while (0)

  // ---- K-loop: B one step ahead, A just-in-time, no barriers (R11-exact) ----
  LOADB(B0, 0);
  LOADB(B1, 1);
  for (int t = 0; t < NSTEP; t += 2) {
    LOADA(t);
    COMPUTE(B0);
    if (t + 2 < NSTEP) LOADB(B0, t + 2);
    LOADA(t + 1);
    COMPUTE(B1);
    if (t + 3 < NSTEP) LOADB(B1, t + 3);
  }

#undef LOADA
#undef LOADB
#undef COMPUTE

  // ---- dump raw p-values (+bias) into LDS, fragment-native indexing ----
  #pragma unroll
  for (int mf = 0; mf < 4; ++mf)
    #pragma unroll
    for (int r = 0; r < 4; ++r) {
      const int pr = wmu * 64 + mf * 16 + ((lane >> 4) << 2) + r;
      sh->raw[pr * 17 + ridx] = acc[mf][r] + sh->bias[pr];
    }
  __syncthreads();

  // ---- output-linear decode ----
  const int vs = (S - s0) < 16 ? (S - s0) : 16;
  const int sq0 = tid / 85;
  const int at0 = tid - 85 * sq0;
  #pragma unroll
  for (int a = 0; a < 3; ++a) {
    const float aw = anchW<HEAD>(a);
    const float ah = anchH<HEAD>(a);
    float* oa = out + ((size_t)(b * 3 + a) * S + s0) * 85;
    int i = tid, at = at0, sq = sq0;
    #pragma unroll
    for (int j = 0; j < 6; ++j) {
      if (i < 1360 && sq < vs) {
        const int pr  = (int)sh->perm[a * 85 + at];
        const float p = sh->raw[pr * 17 + sq];
        const float e  = __expf(p);
        const float sg = e * __builtin_amdgcn_rcpf(e + 1.f);
        const f32x2 c  = sh->cw[sq];
        float val;
        if      (at == 0) val = fmaf(sg, invWD, c[0]);
        else if (at == 1) val = fmaf(sg, invWD, c[1]);
        else if (at == 2) val = e * aw;
        else if (at == 3) val = e * ah;
        else              val = sg;
        oa[i] = val;
      }
      i += 256; at += 1; sq += 3;
      if (at >= 85) { at -= 85; sq += 1; }
    }
  }
}

__global__ __launch_bounds__(256, 7)
void yolo_fused(const float* __restrict__ f13, const float* __restrict__ f26,
                const float* __restrict__ f52,
                const u16* __restrict__ p13, const float* __restrict__ b13,
                const u16* __restrict__ p26, const float* __restrict__ b26,
                const u16* __restrict__ p52, const float* __restrict__ b52,
                float* __restrict__ out)
{
  __shared__ Shm sh;
  const int blk = (int)blockIdx.x;
  float* out13 = out;
  float* out26 = out + 1379040;          // 32*507*85
  float* out52 = out + 6895200;          // + 32*2028*85
  if (blk < 352)        head_block<1024, 13, 0>(f13, p13, b13, out13, blk,        &sh);
  else if (blk < 1728)  head_block< 512, 26, 1>(f26, p26, b26, out26, blk - 352,  &sh);
  else                  head_block< 256, 52, 2>(f52, p52, b52, out52, blk - 1728, &sh);
}

extern "C" void kernel_launch(void* const* d_in, const int* in_sizes, int n_in,
                              void* d_out, int out_size, void* d_ws, size_t ws_size,
                              hipStream_t stream) {
  (void)in_sizes; (void)n_in; (void)ws_size; (void)out_size;
  const float* f13 = (const float*)d_in[0];
  const float* f26 = (const float*)d_in[1];
  const float* f52 = (const float*)d_in[2];
  const float* W13 = (const float*)d_in[3];
  const float* b13 = (const float*)d_in[4];
  const float* W26 = (const float*)d_in[5];
  const float* b26 = (const float*)d_in[6];
  const float* W52 = (const float*)d_in[7];
  const float* b52 = (const float*)d_in[8];

  u16* p13 = (u16*)d_ws;                 // 278528 u16
  u16* p26 = p13 + 278528;               // 139264 u16
  u16* p52 = p26 + 139264;               //  69632 u16 (total 974848 B)

  pack_all<<<dim3(1792), dim3(256), 0, stream>>>(W13, W26, W52, p13, p26, p52);
  // head13: 32x11=352 blocks (K=1024 first); head26: 32x43=1376; head52: 32x169=5408.
  yolo_fused<<<dim3(7136), dim3(256), 0, stream>>>(
      f13, f26, f52, p13, b13, p26, b26, p52, b52, (float*)d_out);
}

// Round 20
// 119.680 us; speedup vs baseline: 2.2672x; 1.0315x over previous
//
#include <hip/hip_runtime.h>
#include <hip/hip_bf16.h>
#include <stdint.h>

typedef float  f32x4  __attribute__((ext_vector_type(4)));
typedef float  f32x2  __attribute__((ext_vector_type(2)));
typedef short  s16x8  __attribute__((ext_vector_type(8)));
typedef unsigned short u16;

#define DEVI __device__ __forceinline__

DEVI u16 f2bf(float x) {
  union { __hip_bfloat16 b; u16 u; } c;
  c.b = __float2bfloat16(x);            // RNE
  return c.u;
}
DEVI float bf2f(u16 h) { return __uint_as_float(((uint32_t)h) << 16); }

// Row permutation: exp-sensitive rows (m=2,3,87,88,172,173) -> permuted rows 0..5
// so the hi/lo correction MFMA only touches fragment rows 0..15 (wave 0).
DEVI int unperm(int pr) {
  if (pr < 6) return 85 * (pr >> 1) + 2 + (pr & 1);
  int idx = pr - 6;
  return idx + (idx < 2 ? 0 : (idx < 85 ? 2 : (idx < 168 ? 4 : 6)));
}

template<int HEAD> DEVI float anchW(int a) {
  if constexpr (HEAD == 0) return a == 0 ? 116.f/416.f : (a == 1 ? 156.f/416.f : 373.f/416.f);
  else if constexpr (HEAD == 1) return a == 0 ? 30.f/416.f : (a == 1 ? 62.f/416.f : 59.f/416.f);
  else return a == 0 ? 10.f/416.f : (a == 1 ? 16.f/416.f : 33.f/416.f);
}
template<int HEAD> DEVI float anchH(int a) {
  if constexpr (HEAD == 0) return a == 0 ? 90.f/416.f : (a == 1 ? 198.f/416.f : 326.f/416.f);
  else if constexpr (HEAD == 1) return a == 0 ? 61.f/416.f : (a == 1 ? 45.f/416.f : 119.f/416.f);
  else return a == 0 ? 13.f/416.f : (a == 1 ? 30.f/416.f : 23.f/416.f);
}

// ---------------- W pre-pack (fragment-linear, unchanged from R7+) ----------------
template<int K, int LOGK>
DEVI void pack_head(const float* __restrict__ Wt, u16* __restrict__ dst,
                    int i, int alBaseWords) {
  const int pr = i >> LOGK;
  const int k  = i & (K - 1);
  float x = 0.f;
  if (pr < 255) x = Wt[(size_t)unperm(pr) * K + k];
  const u16 hi = f2bf(x);
  const int t    = k >> 5;
  const int rb   = pr >> 4;
  const int lane = (pr & 15) | (((k >> 3) & 3) << 4);
  const int elem = k & 7;
  dst[((size_t)(t * 16 + rb)) * 512 + lane * 8 + elem] = hi;
  if (pr < 16)
    dst[(size_t)alBaseWords + (size_t)t * 512 + lane * 8 + elem] = f2bf(x - bf2f(hi));
}

__global__ __launch_bounds__(256)
void pack_all(const float* __restrict__ W13, const float* __restrict__ W26,
              const float* __restrict__ W52, u16* __restrict__ p13,
              u16* __restrict__ p26, u16* __restrict__ p52) {
  const int g = (int)(blockIdx.x * 256 + threadIdx.x);
  if (g < 262144)       pack_head<1024, 10>(W13, p13, g,            262144);
  else if (g < 393216)  pack_head< 512,  9>(W26, p26, g - 262144,   131072);
  else                  pack_head< 256,  8>(W52, p52, g - 393216,    65536);
}

struct Shm {
  float raw[256 * 17];
  float bias[256];
  u16   perm[256];
  f32x2 cw[16];
};

// ---------------- fused GEMM + lean decode ----------------
// R11/R19 structure (bench-best 123-124us, VGPR 36, zero spill) with ONE change:
// in the K-loop, LOADA(t+1) is issued BEFORE LOADB(B0,t+2). vmcnt is a FIFO:
// consuming the NEWEST load forces vmcnt(0), draining all older prefetches.
// R11's order made COMPUTE(B1)'s A-wait drain the just-issued B(t+2) (~800cyc
// HBM exposure every odd step). With A older than the B prefetch, the wait is
// vmcnt(8) and B(t+2) stays in flight a full step.
template<int K, int WD, int HEAD>
DEVI void head_block(const float* __restrict__ F, const u16* __restrict__ Wp,
                     const float* __restrict__ bias_g, float* __restrict__ out,
                     int bidx, Shm* sh)
{
  constexpr int S  = WD * WD;
  constexpr int NT = (S + 15) / 16;
  constexpr int NSTEP = K / 32;          // 32/16/8 — even
  constexpr float invWD = 1.f / (float)WD;

  const int b  = bidx / NT;
  const int s0 = (bidx - b * NT) * 16;
  const int tid  = (int)threadIdx.x;
  const int lane = tid & 63;
  const int wmu  = (int)__builtin_amdgcn_readfirstlane((unsigned)(tid >> 6));
  const int ridx = lane & 15;
  const int g8   = (lane >> 4) << 3;

  // ---- per-block tables ----
  {
    const int m_of = unperm(tid);
    sh->perm[m_of] = (u16)tid;
    sh->bias[tid] = (tid < 255) ? bias_g[m_of] : 0.f;
    if (tid < 16) {
      int s = s0 + tid; if (s >= S) s = S - 1;
      const int hh = s / WD;
      const int ww = s - hh * WD;
      sh->cw[tid] = f32x2{(float)ww * invWD, (float)hh * invWD};
    }
  }

  const float* Fb = F + (size_t)b * K * S;
  const int bc   = s0 + ridx;
  const int bcol = bc < S ? bc : S - 1;
  int boff[8];
  #pragma unroll
  for (int e = 0; e < 8; ++e) boff[e] = (g8 + e) * S + bcol;

  const u16* Abase  = Wp + (size_t)wmu * 4 * 512 + lane * 8;
  const u16* Albase = Wp + (size_t)K * 256 + lane * 8;

  f32x4 acc[4];
  #pragma unroll
  for (int i = 0; i < 4; ++i)
    #pragma unroll
    for (int r = 0; r < 4; ++r) acc[i][r] = 0.f;

  s16x8 A[4], Alo;
  float B0[8], B1[8];

#define LOADA(tt) do {                                                        \
    const u16* ap_ = Abase + (size_t)(tt) * 16 * 512;                         \
    A[0] = *(const s16x8*)(ap_);                                              \
    A[1] = *(const s16x8*)(ap_ + 512);                                        \
    A[2] = *(const s16x8*)(ap_ + 1024);                                       \
    A[3] = *(const s16x8*)(ap_ + 1536);                                       \
    if (wmu == 0) Alo = *(const s16x8*)(Albase + (size_t)(tt) * 512);         \
  } while (0)

#define LOADB(Bx, tt) do {                                                    \
    const float* fp_ = Fb + (size_t)(tt) * 32 * S;                            \
    _Pragma("unroll")                                                         \
    for (int e_ = 0; e_ < 8; ++e_) Bx[e_] = fp_[boff[e_]];                    \
  } while (0)

#define COMPUTE(Bx) do {                                                      \
    u16 bh_[8]; s16x8 Bh_;                                                    \
    _Pragma("unroll")                                                         \
    for (int e_ = 0; e_ < 8; ++e_) { bh_[e_] = f2bf(Bx[e_]); Bh_[e_] = (short)bh_[e_]; } \
    _Pragma("unroll")                                                         \
    for (int mf_ = 0; mf_ < 4; ++mf_)                                         \
      acc[mf_] = __builtin_amdgcn_mfma_f32_16x16x32_bf16(A[mf_], Bh_, acc[mf_], 0, 0, 0); \
    if (wmu == 0) {                                                           \
      s16x8 Bl_;                                                              \
      _Pragma("unroll")                                                       \
      for (int e_ = 0; e_ < 8; ++e_) Bl_[e_] = (short)f2bf(Bx[e_] - bf2f(bh_[e_])); \
      acc[0] = __builtin_amdgcn_mfma_f32_16x16x32_bf16(A[0], Bl_, acc[0], 0, 0, 0); \
      acc[0] = __builtin_amdgcn_mfma_f32_16x16x32_bf16(Alo, Bh_, acc[0], 0, 0, 0); \
    }                                                                         \
  } while (0)

  // ---- K-loop: A-before-B-prefetch ordering so the odd-step A-wait is
  // vmcnt(8), not vmcnt(0) (FIFO drain of the fresh B prefetch). ----
  LOADB(B0, 0);
  LOADB(B1, 1);
  for (int t = 0; t < NSTEP; t += 2) {
    LOADA(t);
    COMPUTE(B0);
    LOADA(t + 1);                        // issue A BEFORE the B prefetch
    if (t + 2 < NSTEP) LOADB(B0, t + 2); // newest in FIFO -> survives A-wait
    COMPUTE(B1);
    if (t + 3 < NSTEP) LOADB(B1, t + 3);
  }

#undef LOADA
#undef LOADB
#undef COMPUTE

  // ---- dump raw p-values (+bias) into LDS, fragment-native indexing ----
  #pragma unroll
  for (int mf = 0; mf < 4; ++mf)
    #pragma unroll
    for (int r = 0; r < 4; ++r) {
      const int pr = wmu * 64 + mf * 16 + ((lane >> 4) << 2) + r;
      sh->raw[pr * 17 + ridx] = acc[mf][r] + sh->bias[pr];
    }
  __syncthreads();

  // ---- output-linear decode ----
  const int vs = (S - s0) < 16 ? (S - s0) : 16;
  const int sq0 = tid / 85;
  const int at0 = tid - 85 * sq0;
  #pragma unroll
  for (int a = 0; a < 3; ++a) {
    const float aw = anchW<HEAD>(a);
    const float ah = anchH<HEAD>(a);
    float* oa = out + ((size_t)(b * 3 + a) * S + s0) * 85;
    int i = tid, at = at0, sq = sq0;
    #pragma unroll
    for (int j = 0; j < 6; ++j) {
      if (i < 1360 && sq < vs) {
        const int pr  = (int)sh->perm[a * 85 + at];
        const float p = sh->raw[pr * 17 + sq];
        const float e  = __expf(p);
        const float sg = e * __builtin_amdgcn_rcpf(e + 1.f);
        const f32x2 c  = sh->cw[sq];
        float val;
        if      (at == 0) val = fmaf(sg, invWD, c[0]);
        else if (at == 1) val = fmaf(sg, invWD, c[1]);
        else if (at == 2) val = e * aw;
        else if (at == 3) val = e * ah;
        else              val = sg;
        oa[i] = val;
      }
      i += 256; at += 1; sq += 3;
      if (at >= 85) { at -= 85; sq += 1; }
    }
  }
}

__global__ __launch_bounds__(256, 7)
void yolo_fused(const float* __restrict__ f13, const float* __restrict__ f26,
                const float* __restrict__ f52,
                const u16* __restrict__ p13, const float* __restrict__ b13,
                const u16* __restrict__ p26, const float* __restrict__ b26,
                const u16* __restrict__ p52, const float* __restrict__ b52,
                float* __restrict__ out)
{
  __shared__ Shm sh;
  const int blk = (int)blockIdx.x;
  float* out13 = out;
  float* out26 = out + 1379040;          // 32*507*85
  float* out52 = out + 6895200;          // + 32*2028*85
  if (blk < 352)        head_block<1024, 13, 0>(f13, p13, b13, out13, blk,        &sh);
  else if (blk < 1728)  head_block< 512, 26, 1>(f26, p26, b26, out26, blk - 352,  &sh);
  else                  head_block< 256, 52, 2>(f52, p52, b52, out52, blk - 1728, &sh);
}

extern "C" void kernel_launch(void* const* d_in, const int* in_sizes, int n_in,
                              void* d_out, int out_size, void* d_ws, size_t ws_size,
                              hipStream_t stream) {
  (void)in_sizes; (void)n_in; (void)ws_size; (void)out_size;
  const float* f13 = (const float*)d_in[0];
  const float* f26 = (const float*)d_in[1];
  const float* f52 = (const float*)d_in[2];
  const float* W13 = (const float*)d_in[3];
  const float* b13 = (const float*)d_in[4];
  const float* W26 = (const float*)d_in[5];
  const float* b26 = (const float*)d_in[6];
  const float* W52 = (const float*)d_in[7];
  const float* b52 = (const float*)d_in[8];

  u16* p13 = (u16*)d_ws;                 // 278528 u16
  u16* p26 = p13 + 278528;               // 139264 u16
  u16* p52 = p26 + 139264;               //  69632 u16 (total 974848 B)

  pack_all<<<dim3(1792), dim3(256), 0, stream>>>(W13, W26, W52, p13, p26, p52);
  // head13: 32x11=352 blocks (K=1024 first); head26: 32x43=1376; head52: 32x169=5408.
  yolo_fused<<<dim3(7136), dim3(256), 0, stream>>>(
      f13, f26, f52, p13, b13, p26, b26, p52, b52, (float*)d_out);
}